// Round 1
// baseline (156.491 us; speedup 1.0000x reference)
//
#include <hip/hip_runtime.h>
#include <math.h>

#define DD 160
#define HH 192
#define WW 160
#define TW 32
#define TH 8
#define TD 16
#define HW (HH * WW)
#define NVOX (DD * HH * WW)
#define HTW (TW + 2)            // 34
#define HTH (TH + 2)            // 10
#define HALO (HTW * HTH)        // 340

__device__ __forceinline__ int mod3(int x) { return ((x % 3) + 3) % 3; }

__global__ __launch_bounds__(256) void demons_ori_kernel(
    const float* __restrict__ Mv, const float* __restrict__ Sv,
    const float* __restrict__ flow, float* __restrict__ out)
{
    // LDS: raw 3-slice ring per field + staged A (box-d) and Dz (diff-d) planes
    __shared__ float raw[2][3][HTH][HTW];   // [field][ring][h][w]
    __shared__ float Aa[2][HTH][HTW];
    __shared__ float Dz[2][HTH][HTW];
    __shared__ float redbuf[4];

    const int tid = threadIdx.x;
    const int tw = tid & 31;
    const int th = tid >> 5;

    const int w0 = blockIdx.x * TW;
    const int h0 = blockIdx.y * TH;
    const int d0 = blockIdx.z * TD;

    // ---- slice loader: global (zero-padded) -> raw ring slot ----
    auto load_slice = [&](int d, int slot) {
        const bool din = (d >= 0) && (d < DD);
        for (int i = tid; i < HALO; i += 256) {
            int hh = i / HTW;
            int ww = i - hh * HTW;
            int gh = h0 + hh - 1;
            int gw = w0 + ww - 1;
            float vs = 0.f, vm = 0.f;
            if (din && gh >= 0 && gh < HH && gw >= 0 && gw < WW) {
                size_t off = (size_t)d * HW + (size_t)gh * WW + gw;
                vs = Sv[off];
                vm = Mv[off];
            }
            raw[0][slot][hh][ww] = vs;
            raw[1][slot][hh][ww] = vm;
        }
    };

    load_slice(d0 - 1, mod3(d0 - 1));
    load_slice(d0,     mod3(d0));

    float lsum = 0.f;

    for (int dd = 0; dd < TD; ++dd) {
        const int d = d0 + dd;
        const int sm = mod3(d - 1), s0 = mod3(d), sp = mod3(d + 1);

        load_slice(d + 1, sp);
        __syncthreads();

        // ---- stage A = box-d, Dz = central-diff-d over the halo plane ----
        for (int i = tid; i < HALO; i += 256) {
            int hh = i / HTW;
            int ww = i - hh * HTW;
            float xm0 = raw[0][sm][hh][ww];
            float x00 = raw[0][s0][hh][ww];
            float xp0 = raw[0][sp][hh][ww];
            Aa[0][hh][ww] = xm0 + x00 + xp0;
            Dz[0][hh][ww] = xp0 - xm0;
            float xm1 = raw[1][sm][hh][ww];
            float x01 = raw[1][s0][hh][ww];
            float xp1 = raw[1][sp][hh][ww];
            Aa[1][hh][ww] = xm1 + x01 + xp1;
            Dz[1][hh][ww] = xp1 - xm1;
        }
        __syncthreads();

        // ---- per-voxel: in-plane 3x3 stencils on A/Dz ----
        const int hc = th + 1, wc = tw + 1;
        float gx[2], gy[2], gz[2];
        #pragma unroll
        for (int f = 0; f < 2; ++f) {
            float a_mm = Aa[f][hc - 1][wc - 1];
            float a_m0 = Aa[f][hc - 1][wc];
            float a_mp = Aa[f][hc - 1][wc + 1];
            float a_0m = Aa[f][hc][wc - 1];
            float a_0p = Aa[f][hc][wc + 1];
            float a_pm = Aa[f][hc + 1][wc - 1];
            float a_p0 = Aa[f][hc + 1][wc];
            float a_pp = Aa[f][hc + 1][wc + 1];
            gx[f] = (a_mp + 2.f * a_0p + a_pp) - (a_mm + 2.f * a_0m + a_pm);
            gy[f] = (a_pm + 2.f * a_p0 + a_pp) - (a_mm + 2.f * a_m0 + a_mp);
            float d_mm = Dz[f][hc - 1][wc - 1];
            float d_m0 = Dz[f][hc - 1][wc];
            float d_mp = Dz[f][hc - 1][wc + 1];
            float d_0m = Dz[f][hc][wc - 1];
            float d_00 = Dz[f][hc][wc];
            float d_0p = Dz[f][hc][wc + 1];
            float d_pm = Dz[f][hc + 1][wc - 1];
            float d_p0 = Dz[f][hc + 1][wc];
            float d_pp = Dz[f][hc + 1][wc + 1];
            gz[f] = (d_mm + d_m0 + d_mp) + 2.f * (d_0m + d_00 + d_0p)
                  + (d_pm + d_p0 + d_pp);
        }

        float sc = raw[0][s0][hc][wc];
        float mc = raw[1][s0][hc][wc];
        float idf = mc - sc;
        float i2 = idf * idf;
        // f=0 is S, f=1 is M
        float denS = gx[0] * gx[0] + gy[0] * gy[0] + gz[0] * gz[0] + i2 + 1e-10f;
        float denM = gx[1] * gx[1] + gy[1] * gy[1] + gz[1] * gz[1] + i2 + 1e-10f;
        float rS = 1.f / denS;
        float rM = 1.f / denM;
        float Ux = idf * (gx[0] * rS + gx[1] * rM);
        float Uy = idf * (gy[0] * rS + gy[1] * rM);
        float Uz = idf * (gz[0] * rS + gz[1] * rM);
        float rz = 1.f / (Uz + 1e-10f);
        float dxz = atanf(Ux * rz);
        float dyz = atanf(Uy * rz);

        size_t off = (size_t)d * HW + (size_t)(h0 + th) * WW + (w0 + tw);
        float f0 = flow[off];
        float f1 = flow[(size_t)NVOX + off];
        float f2 = flow[2 * (size_t)NVOX + off];
        float rf = 1.f / (f2 + 1e-10f);
        float fxz = atanf(f0 * rf);
        float fyz = atanf(f1 * rf);

        float e1 = fxz - dxz;
        float e2 = fyz - dyz;
        lsum += e1 * e1 + e2 * e2;
        // next iteration: load writes ring slot mod3(d+2) (not read here);
        // A/Dz rewrite is fenced by the __syncthreads after that load.
    }

    // ---- reduction: wave shuffle -> LDS across 4 waves -> one atomic ----
    #pragma unroll
    for (int o = 32; o > 0; o >>= 1)
        lsum += __shfl_down(lsum, o, 64);
    if ((tid & 63) == 0)
        redbuf[tid >> 6] = lsum;
    __syncthreads();
    if (tid == 0) {
        float s = redbuf[0] + redbuf[1] + redbuf[2] + redbuf[3];
        atomicAdd(out, s * (1.0f / (float)NVOX));
    }
}

extern "C" void kernel_launch(void* const* d_in, const int* in_sizes, int n_in,
                              void* d_out, int out_size, void* d_ws, size_t ws_size,
                              hipStream_t stream) {
    const float* Mv   = (const float*)d_in[0];
    const float* Sv   = (const float*)d_in[1];
    const float* flow = (const float*)d_in[2];
    float* out = (float*)d_out;

    hipMemsetAsync(out, 0, sizeof(float), stream);

    dim3 grid(WW / TW, HH / TH, DD / TD);   // 5 x 24 x 10 = 1200 blocks
    demons_ori_kernel<<<grid, dim3(256), 0, stream>>>(Mv, Sv, flow, out);
}

// Round 2
// 153.249 us; speedup vs baseline: 1.0212x; 1.0212x over previous
//
#include <hip/hip_runtime.h>
#include <math.h>

#define DD 160
#define HH 192
#define WW 160
#define TW 32
#define TH 8
#define TD 8
#define HW (HH * WW)
#define NVOX (DD * HH * WW)
#define HTW (TW + 2)            // 34
#define HTH (TH + 2)            // 10
#define HALO (HTW * HTH)        // 340

// atan via odd minimax poly on [0,1] + rcp range reduction; max err ~1e-5 rad
__device__ __forceinline__ float atan_fast(float r) {
    float ar = fabsf(r);
    float inv = __builtin_amdgcn_rcpf(ar);
    bool big = ar > 1.0f;
    float x = big ? inv : ar;
    float x2 = x * x;
    float p = fmaf(x2, fmaf(x2, fmaf(x2, fmaf(x2, fmaf(x2,
              -0.0117212f, 0.05265332f), -0.11643287f), 0.19354346f),
              -0.33262347f), 0.99997726f);
    p *= x;
    float res = big ? (1.57079632679489662f - p) : p;
    return copysignf(res, r);
}

__global__ __launch_bounds__(256) void demons_ori_kernel(
    const float* __restrict__ Mv, const float* __restrict__ Sv,
    const float* __restrict__ flow, float* __restrict__ out)
{
    // double-buffered single raw slice per field; separable d-reuse lives in registers
    __shared__ float buf[2][2][HTH][HTW];   // [parity][field][h][w]
    __shared__ float redbuf[4];

    const int tid = threadIdx.x;
    const int tw = tid & 31;
    const int th = tid >> 5;
    const int w0 = blockIdx.x * TW;
    const int h0 = blockIdx.y * TH;
    const int d0 = blockIdx.z * TD;

    // staging slots are slice-invariant: precompute (<=2 per thread)
    int nst = 0;
    int sidx[2];
    int gbase[2];
    bool gok[2];
    for (int i = tid; i < HALO; i += 256) {
        int hh = i / HTW, ww = i - hh * HTW;
        int gh = h0 + hh - 1, gw = w0 + ww - 1;
        sidx[nst] = i;
        gok[nst] = (gh >= 0 && gh < HH && gw >= 0 && gw < WW);
        gbase[nst] = gh * WW + gw;
        nst++;
    }

    const int hc = th + 1, wc = tw + 1;

    // stage slice d: global -> buf[d&1], then per-thread separable partials
    // pq[f] = {Px (sobel-x in-plane), Py (sobel-y), B ([1,2,1]_h box), center}
    auto stage = [&](int d, float pq[2][4]) {
        float* __restrict__ bS = &buf[d & 1][0][0][0];
        float* __restrict__ bM = &buf[d & 1][1][0][0];
        const bool din = (d >= 0) && (d < DD);
        for (int j = 0; j < nst; ++j) {
            float vs = 0.f, vm = 0.f;
            if (din && gok[j]) {
                size_t off = (size_t)d * HW + gbase[j];
                vs = Sv[off];
                vm = Mv[off];
            }
            bS[sidx[j]] = vs;
            bM[sidx[j]] = vm;
        }
        __syncthreads();   // RAW; WAR across iters is protected by double buffer + this barrier
        #pragma unroll
        for (int f = 0; f < 2; ++f) {
            const float* __restrict__ b = f ? bM : bS;
            const float* r0 = b + (hc - 1) * HTW + (wc - 1);
            const float* r1 = r0 + HTW;
            const float* r2 = r1 + HTW;
            float v00 = r0[0], v01 = r0[1], v02 = r0[2];
            float v10 = r1[0], v11 = r1[1], v12 = r1[2];
            float v20 = r2[0], v21 = r2[1], v22 = r2[2];
            pq[f][0] = (v02 + 2.f * v12 + v22) - (v00 + 2.f * v10 + v20);
            pq[f][1] = (v20 + 2.f * v21 + v22) - (v00 + 2.f * v01 + v02);
            pq[f][2] = (v00 + v01 + v02) + 2.f * (v10 + v11 + v12)
                     + (v20 + v21 + v22);
            pq[f][3] = v11;
        }
    };

    float Pm[2][4], P0[2][4], Pp[2][4];
    stage(d0 - 1, Pm);
    stage(d0, P0);

    float lsum = 0.f;
    const size_t voff0 = (size_t)(h0 + th) * WW + (w0 + tw);

    #pragma unroll
    for (int dd = 0; dd < TD; ++dd) {
        const int d = d0 + dd;
        stage(d + 1, Pp);

        // gx = Px[d-1]+Px[d]+Px[d+1]; gy likewise; gz = B[d+1]-B[d-1]
        float idf = P0[1][3] - P0[0][3];
        float i2 = idf * idf + 1e-10f;
        float gxS = Pm[0][0] + P0[0][0] + Pp[0][0];
        float gyS = Pm[0][1] + P0[0][1] + Pp[0][1];
        float gzS = Pp[0][2] - Pm[0][2];
        float gxM = Pm[1][0] + P0[1][0] + Pp[1][0];
        float gyM = Pm[1][1] + P0[1][1] + Pp[1][1];
        float gzM = Pp[1][2] - Pm[1][2];
        float denS = gxS * gxS + gyS * gyS + gzS * gzS + i2;
        float denM = gxM * gxM + gyM * gyM + gzM * gzM + i2;
        float rS = __builtin_amdgcn_rcpf(denS);
        float rM = __builtin_amdgcn_rcpf(denM);
        float Ux = idf * (gxS * rS + gxM * rM);
        float Uy = idf * (gyS * rS + gyM * rM);
        float Uz = idf * (gzS * rS + gzM * rM);
        float rz = __builtin_amdgcn_rcpf(Uz + 1e-10f);
        float dxz = atan_fast(Ux * rz);
        float dyz = atan_fast(Uy * rz);

        size_t off = (size_t)d * HW + voff0;
        float f0 = flow[off];
        float f1 = flow[(size_t)NVOX + off];
        float f2 = flow[2 * (size_t)NVOX + off];
        float rf = __builtin_amdgcn_rcpf(f2 + 1e-10f);
        float fxz = atan_fast(f0 * rf);
        float fyz = atan_fast(f1 * rf);

        float e1 = fxz - dxz;
        float e2 = fyz - dyz;
        lsum += e1 * e1 + e2 * e2;

        #pragma unroll
        for (int f = 0; f < 2; ++f)
            #pragma unroll
            for (int q = 0; q < 4; ++q) {
                Pm[f][q] = P0[f][q];
                P0[f][q] = Pp[f][q];
            }
    }

    // wave shuffle -> LDS across 4 waves -> one atomic per block
    #pragma unroll
    for (int o = 32; o > 0; o >>= 1)
        lsum += __shfl_down(lsum, o, 64);
    if ((tid & 63) == 0)
        redbuf[tid >> 6] = lsum;
    __syncthreads();
    if (tid == 0) {
        float s = redbuf[0] + redbuf[1] + redbuf[2] + redbuf[3];
        atomicAdd(out, s * (1.0f / (float)NVOX));
    }
}

extern "C" void kernel_launch(void* const* d_in, const int* in_sizes, int n_in,
                              void* d_out, int out_size, void* d_ws, size_t ws_size,
                              hipStream_t stream) {
    const float* Mv   = (const float*)d_in[0];
    const float* Sv   = (const float*)d_in[1];
    const float* flow = (const float*)d_in[2];
    float* out = (float*)d_out;

    hipMemsetAsync(out, 0, sizeof(float), stream);

    dim3 grid(WW / TW, HH / TH, DD / TD);   // 5 x 24 x 20 = 2400 blocks
    demons_ori_kernel<<<grid, dim3(256), 0, stream>>>(Mv, Sv, flow, out);
}